// Round 10
// baseline (383.927 us; speedup 1.0000x reference)
//
#include <hip/hip_runtime.h>
#include <hip/hip_bf16.h>

typedef unsigned short u16;
typedef unsigned int u32;
typedef __attribute__((ext_vector_type(8))) short bf16x8;   // 8 bf16 = 4 VGPR
typedef __attribute__((ext_vector_type(16))) float f32x16;  // 32x32 C/D frag
typedef _Float16 h16x2 __attribute__((ext_vector_type(2)));

#define NBUCK  1024      // pow2 >= 782 buckets
#define BSHIFT 7         // 128 nodes per bucket

static __device__ __forceinline__ u16 f2bf(float f) {
    __hip_bfloat16 b = __float2bfloat16(f);   // RNE
    return *(u16*)&b;
}

// ---------------------------------------------------------------------------
// Kernel 0: build W1's MFMA fragment table ONCE (node-independent) and zero
// the bucket histogram (d_ws is re-poisoned to 0xAA before every launch).
// wtab flat = ((ct*4+ks)*64+lane)*8+j  holds (bf16) Wcat[k][c],
//   k = ks*16+(lane>>5)*8+j,  c = ct*32+(lane&31),
//   Wcat[k][c] = c<64 ? W1[k][c] : W1[64+k][c-64].
// ---------------------------------------------------------------------------
__global__ __launch_bounds__(256) void build_wfrag(
    const float* __restrict__ W1, u16* __restrict__ wtab, u32* __restrict__ hist)
{
    const int flat = blockIdx.x * 256 + threadIdx.x;
    if (flat < NBUCK) hist[flat] = 0;
    if (flat >= 8192) return;
    const int j    = flat & 7;
    const int lane = (flat >> 3) & 63;
    const int ks   = (flat >> 9) & 3;
    const int ct   = flat >> 11;
    const int k = ks * 16 + (lane >> 5) * 8 + j;
    const int c = ct * 32 + (lane & 31);
    const float v = (c < 64) ? W1[(size_t)k * 64 + c]
                             : W1[(size_t)(64 + k) * 64 + (c - 64)];
    wtab[flat] = f2bf(v);
}

// ---------------------------------------------------------------------------
// Kernel A (MFMA, swapped operands): D[c][node]; lane owns one node's pq row.
//   pq[n][c]: c<64 (P): b1[c]+sum_k z[n][k]W1[k][c]; c>=64 (Q): sum_k z W1[64+k]
// ---------------------------------------------------------------------------
__global__ __launch_bounds__(256) void node_mfma(
    const float* __restrict__ z, const u16* __restrict__ wtab,
    const float* __restrict__ b1, u16* __restrict__ pq, int nNodes)
{
    const int lane   = threadIdx.x & 63;
    const int wave   = threadIdx.x >> 6;
    const int l31    = lane & 31;
    const int half   = lane >> 5;
    const int nodeBase = (blockIdx.x * 4 + wave) * 32;
    if (nodeBase >= nNodes) return;

    const bf16x8* wt = (const bf16x8*)wtab;
    bf16x8 Wf[4][4];
#pragma unroll
    for (int ct = 0; ct < 4; ++ct)
#pragma unroll
        for (int ks = 0; ks < 4; ++ks)
            Wf[ct][ks] = wt[(ct * 4 + ks) * 64 + lane];

    int zrowi = nodeBase + l31;
    if (zrowi > nNodes - 1) zrowi = nNodes - 1;
    const float* zrow = z + (size_t)zrowi * 64;
    bf16x8 Zf[4];
#pragma unroll
    for (int ks = 0; ks < 4; ++ks) {
        const float4 v0 = *(const float4*)(zrow + ks * 16 + half * 8);
        const float4 v1 = *(const float4*)(zrow + ks * 16 + half * 8 + 4);
        Zf[ks][0] = (short)f2bf(v0.x); Zf[ks][1] = (short)f2bf(v0.y);
        Zf[ks][2] = (short)f2bf(v0.z); Zf[ks][3] = (short)f2bf(v0.w);
        Zf[ks][4] = (short)f2bf(v1.x); Zf[ks][5] = (short)f2bf(v1.y);
        Zf[ks][6] = (short)f2bf(v1.z); Zf[ks][7] = (short)f2bf(v1.w);
    }

    f32x16 acc[4];
#pragma unroll
    for (int ct = 0; ct < 4; ++ct) acc[ct] = (f32x16)(0.0f);
#pragma unroll
    for (int ks = 0; ks < 4; ++ks)
#pragma unroll
        for (int ct = 0; ct < 4; ++ct)
            acc[ct] = __builtin_amdgcn_mfma_f32_32x32x16_bf16(
                Wf[ct][ks], Zf[ks], acc[ct], 0, 0, 0);

    const int node = nodeBase + l31;
    if (node < nNodes) {
        u16* prow = pq + (size_t)node * 128;
#pragma unroll
        for (int ct = 0; ct < 4; ++ct) {
#pragma unroll
            for (int g = 0; g < 4; ++g) {
                const int c0 = ct * 32 + 8 * g + 4 * half;
                float v0 = acc[ct][4 * g + 0];
                float v1 = acc[ct][4 * g + 1];
                float v2 = acc[ct][4 * g + 2];
                float v3 = acc[ct][4 * g + 3];
                if (ct < 2) {
                    v0 += b1[c0 + 0]; v1 += b1[c0 + 1];
                    v2 += b1[c0 + 2]; v3 += b1[c0 + 3];
                }
                uint2 st;
                st.x = __builtin_bit_cast(u32, __builtin_amdgcn_cvt_pkrtz(v0, v1));
                st.y = __builtin_bit_cast(u32, __builtin_amdgcn_cvt_pkrtz(v2, v3));
                *(uint2*)(prow + c0) = st;
            }
        }
    }
}

// ---------------------------------------------------------------------------
// Kernel H: histogram of edges per source-bucket (b = i >> 7). LDS-aggregated.
// ---------------------------------------------------------------------------
__global__ __launch_bounds__(256) void hist_k(
    const int* __restrict__ e0, u32* __restrict__ hist, int E)
{
    __shared__ u32 lh[NBUCK];
    for (int t = threadIdx.x; t < NBUCK; t += 256) lh[t] = 0;
    __syncthreads();
    for (int e = blockIdx.x * 256 + threadIdx.x; e < E; e += gridDim.x * 256)
        atomicAdd(&lh[((u32)e0[e]) >> BSHIFT], 1);
    __syncthreads();
    for (int t = threadIdx.x; t < NBUCK; t += 256)
        if (lh[t]) atomicAdd(&hist[t], lh[t]);
}

// ---------------------------------------------------------------------------
// Kernel S: exclusive prefix-sum of hist -> base[], init cursor[]. 1 block.
// ---------------------------------------------------------------------------
__global__ __launch_bounds__(1024) void scan_k(
    const u32* __restrict__ hist, u32* __restrict__ base, u32* __restrict__ cursor)
{
    __shared__ u32 s[NBUCK];
    const int t = threadIdx.x;
    const u32 mine = hist[t];
    s[t] = mine;
    __syncthreads();
    for (int off = 1; off < NBUCK; off <<= 1) {
        u32 v = (t >= off) ? s[t - off] : 0;
        __syncthreads();
        s[t] += v;
        __syncthreads();
    }
    const u32 ex = s[t] - mine;    // exclusive
    base[t] = ex;
    cursor[t] = ex;
    if (t == NBUCK - 1) base[NBUCK] = s[t];
}

// ---------------------------------------------------------------------------
// Kernel T: scatter edges into bucket order. rec = {j, e | (i&127)<<20}
// (E < 2^20 so e fits in 20 bits; i&127 is the P-row index within bucket).
// ---------------------------------------------------------------------------
__global__ __launch_bounds__(256) void scatter_k(
    const int* __restrict__ e0, const int* __restrict__ e1,
    u32* __restrict__ cursor, uint2* __restrict__ recs, int E)
{
    const int e = blockIdx.x * 256 + threadIdx.x;
    if (e >= E) return;
    const u32 i = (u32)e0[e];
    const u32 j = (u32)e1[e];
    const u32 pos = atomicAdd(&cursor[i >> BSHIFT], 1);
    uint2 r; r.x = j; r.y = (u32)e | ((i & 127u) << 20);
    recs[pos] = r;
}

// ---------------------------------------------------------------------------
// Kernel P: per-bucket edge processing. Block b stages its 128 P-rows
// (128 x 64 fp16 = 16 KB) in LDS, then 8 lanes/edge: P from LDS, Q gathered.
//   out[e] = b2 + sum_h W2[h] * relu(P[i][h] + Q[j][h])
// P-half of the gather (128 MB fabric traffic) is eliminated.
// ---------------------------------------------------------------------------
__global__ __launch_bounds__(256) void process_k(
    const uint2* __restrict__ recs, const u32* __restrict__ base,
    const u16* __restrict__ pq, const float* __restrict__ W2,
    const float* __restrict__ b2, float* __restrict__ out, int nNodes)
{
    __shared__ u16 Plds[128 * 64];             // 16 KB: P half of 128 rows
    const int b   = blockIdx.x;
    const int nb0 = b << BSHIFT;
    const int tid = threadIdx.x;

    const int nrows = (nNodes - nb0 > 128) ? 128 : (nNodes - nb0);
    // stage: flat f over nrows*8 uint4 chunks; row r chunk c -> pq[(nb0+r)*128 + c*8]
    for (int f = tid; f < nrows * 8; f += 256) {
        const int r = f >> 3, c = f & 7;
        ((uint4*)Plds)[r * 8 + c] =
            ((const uint4*)(pq + (size_t)(nb0 + r) * 128))[c];
    }
    __syncthreads();

    const int g   = tid >> 3;   // 32 groups of 8 lanes
    const int sub = tid & 7;

    const float4 wa = ((const float4*)W2)[2 * sub];
    const float4 wb = ((const float4*)W2)[2 * sub + 1];
    h16x2 w2h[4];
    w2h[0] = (h16x2){(_Float16)wa.x, (_Float16)wa.y};
    w2h[1] = (h16x2){(_Float16)wa.z, (_Float16)wa.w};
    w2h[2] = (h16x2){(_Float16)wb.x, (_Float16)wb.y};
    w2h[3] = (h16x2){(_Float16)wb.z, (_Float16)wb.w};
    const h16x2 hzero = (h16x2){(_Float16)0.0f, (_Float16)0.0f};
    const float bias = b2[0];

    const u32 lo = base[b], hi = base[b + 1];
    for (u32 s = lo + g; s < hi; s += 32) {
        const uint2 r = recs[s];               // 8 lanes broadcast
        const u32 j  = r.x;
        const u32 e  = r.y & 0xFFFFFu;
        const u32 il = r.y >> 20;              // i & 127

        const uint4 p = ((const uint4*)&Plds[il * 64])[sub];          // LDS
        const uint4 q = ((const uint4*)(pq + (size_t)j * 128 + 64))[sub];

        const u32 pw[4] = {p.x, p.y, p.z, p.w};
        const u32 qw[4] = {q.x, q.y, q.z, q.w};
        float sum = 0.0f;
#pragma unroll
        for (int c = 0; c < 4; ++c) {
            h16x2 pp = __builtin_bit_cast(h16x2, pw[c]);
            h16x2 qq = __builtin_bit_cast(h16x2, qw[c]);
            h16x2 a  = __builtin_elementwise_max(pp + qq, hzero);
#if __has_builtin(__builtin_amdgcn_fdot2)
            sum = __builtin_amdgcn_fdot2(a, w2h[c], sum, false);
#else
            sum = fmaf((float)a[0], (float)w2h[c][0],
                  fmaf((float)a[1], (float)w2h[c][1], sum));
#endif
        }
        sum += __shfl_xor(sum, 1);
        sum += __shfl_xor(sum, 2);
        sum += __shfl_xor(sum, 4);
        if (sub == 0) out[e] = sum + bias;
    }
}

// ---------------------------------------------------------------------------
extern "C" void kernel_launch(void* const* d_in, const int* in_sizes, int n_in,
                              void* d_out, int out_size, void* d_ws, size_t ws_size,
                              hipStream_t stream) {
    const float* z  = (const float*)d_in[0];
    const int*   eg = (const int*)d_in[1];
    const float* W1 = (const float*)d_in[2];
    const float* b1 = (const float*)d_in[3];
    const float* W2 = (const float*)d_in[4];
    const float* b2 = (const float*)d_in[5];
    float* out = (float*)d_out;

    const int nNodes = in_sizes[0] / 64;   // 100000
    const int E      = in_sizes[1] / 2;    // 1000000

    // ---- workspace layout (all 256-B aligned) ----
    char* w = (char*)d_ws;
    u16*   wtab   = (u16*)w;                          //    16 KB
    u16*   pq     = (u16*)(w + 16384);                //  25.6 MB
    char*  p2     = w + 16384 + (size_t)nNodes * 256; //  = 25,616,384
    u32*   hist   = (u32*)p2;                         //   4 KB
    u32*   base   = (u32*)(p2 + 4352);                //   4.1 KB (NBUCK+1)
    u32*   cursor = (u32*)(p2 + 8704);                //   4 KB
    uint2* recs   = (uint2*)(p2 + 13056);             //   8 MB

    build_wfrag<<<dim3(32), dim3(256), 0, stream>>>(W1, wtab, hist);

    dim3 gA((nNodes + 127) / 128);         // 4 waves x 32 nodes per block
    node_mfma<<<gA, dim3(256), 0, stream>>>(z, wtab, b1, pq, nNodes);

    hist_k<<<dim3(256), dim3(256), 0, stream>>>(eg, hist, E);
    scan_k<<<dim3(1), dim3(1024), 0, stream>>>(hist, base, cursor);
    scatter_k<<<dim3((E + 255) / 256), dim3(256), 0, stream>>>(
        eg, eg + E, cursor, recs, E);

    const int nbUsed = (nNodes + 127) >> BSHIFT;      // 782
    process_k<<<dim3(nbUsed), dim3(256), 0, stream>>>(
        recs, base, pq, W2, b2, out, nNodes);
}

// Round 11
// 128.908 us; speedup vs baseline: 2.9783x; 2.9783x over previous
//
#include <hip/hip_runtime.h>
#include <hip/hip_bf16.h>

typedef unsigned short u16;
typedef unsigned int u32;
typedef __attribute__((ext_vector_type(8))) short bf16x8;   // 8 bf16 = 4 VGPR
typedef __attribute__((ext_vector_type(16))) float f32x16;  // 32x32 C/D frag
typedef _Float16 h16x2 __attribute__((ext_vector_type(2)));

static __device__ __forceinline__ u16 f2bf(float f) {
    __hip_bfloat16 b = __float2bfloat16(f);   // RNE
    return *(u16*)&b;
}

// ---------------------------------------------------------------------------
// Kernel 0: build W1's MFMA fragment table ONCE (node-independent).
// wtab flat = ((ct*4+ks)*64+lane)*8+j  holds (bf16) Wcat[k][c],
//   k = ks*16+(lane>>5)*8+j,  c = ct*32+(lane&31),
//   Wcat[k][c] = c<64 ? W1[k][c] : W1[64+k][c-64].
// Serves as the MFMA *A* operand for the swapped product D = Wcat^T . z
// (A and B fragments share the same (lane&31, (lane>>5)*8+j) indexing).
// ---------------------------------------------------------------------------
__global__ __launch_bounds__(256) void build_wfrag(
    const float* __restrict__ W1, u16* __restrict__ wtab)
{
    const int flat = blockIdx.x * 256 + threadIdx.x;
    if (flat >= 8192) return;
    const int j    = flat & 7;
    const int lane = (flat >> 3) & 63;
    const int ks   = (flat >> 9) & 3;
    const int ct   = flat >> 11;
    const int k = ks * 16 + (lane >> 5) * 8 + j;
    const int c = ct * 32 + (lane & 31);
    const float v = (c < 64) ? W1[(size_t)k * 64 + c]
                             : W1[(size_t)(64 + k) * 64 + (c - 64)];
    wtab[flat] = f2bf(v);
}

// ---------------------------------------------------------------------------
// Kernel A (MFMA, swapped operands, col-split): computes D[c][node] for
// col-tiles ct = 2*blockIdx.y + {0,1}. Lane owns one node's HALF pq row.
//   pq[n][c]: c<64 (P): b1[c]+sum_k z[n][k]W1[k][c]; c>=64 (Q): sum_k zW1[64+k]
// Split halves acc/W-frag register state (VGPR ~128 -> ~80) and doubles
// resident waves (1564 blocks) to hide the z-gather latency that kept node
// at ~25 us (vs 8 us streaming floor) in R4-R9.
// D: col = lane&31 = node-in-tile, row = (reg&3)+8*(reg>>2)+4*(lane>>5) = c.
// ---------------------------------------------------------------------------
__global__ __launch_bounds__(256) void node_mfma(
    const float* __restrict__ z, const u16* __restrict__ wtab,
    const float* __restrict__ b1, u16* __restrict__ pq, int nNodes)
{
    const int lane   = threadIdx.x & 63;
    const int wave   = threadIdx.x >> 6;
    const int l31    = lane & 31;
    const int half   = lane >> 5;
    const int ch     = blockIdx.y;            // col-half: 0 -> P, 1 -> Q
    const int nodeBase = (blockIdx.x * 4 + wave) * 32;
    if (nodeBase >= nNodes) return;

    // ---- W fragments (A operand) for this col-half: 8 coalesced 16-B loads
    const bf16x8* wt = (const bf16x8*)wtab;
    bf16x8 Wf[2][4];
#pragma unroll
    for (int ctl = 0; ctl < 2; ++ctl)
#pragma unroll
        for (int ks = 0; ks < 4; ++ks)
            Wf[ctl][ks] = wt[((2 * ch + ctl) * 4 + ks) * 64 + lane];

    // ---- z fragments (B operand): Zf[ks][j] = z[nodeBase+l31][ks*16+half*8+j]
    int zrowi = nodeBase + l31;
    if (zrowi > nNodes - 1) zrowi = nNodes - 1;       // clamp (safe redundant)
    const float* zrow = z + (size_t)zrowi * 64;
    bf16x8 Zf[4];
#pragma unroll
    for (int ks = 0; ks < 4; ++ks) {
        const float4 v0 = *(const float4*)(zrow + ks * 16 + half * 8);
        const float4 v1 = *(const float4*)(zrow + ks * 16 + half * 8 + 4);
        Zf[ks][0] = (short)f2bf(v0.x); Zf[ks][1] = (short)f2bf(v0.y);
        Zf[ks][2] = (short)f2bf(v0.z); Zf[ks][3] = (short)f2bf(v0.w);
        Zf[ks][4] = (short)f2bf(v1.x); Zf[ks][5] = (short)f2bf(v1.y);
        Zf[ks][6] = (short)f2bf(v1.z); Zf[ks][7] = (short)f2bf(v1.w);
    }

    // ---- MFMA accumulate (A = W, B = z)
    f32x16 acc[2];
    acc[0] = (f32x16)(0.0f);
    acc[1] = (f32x16)(0.0f);
#pragma unroll
    for (int ks = 0; ks < 4; ++ks)
#pragma unroll
        for (int ctl = 0; ctl < 2; ++ctl)
            acc[ctl] = __builtin_amdgcn_mfma_f32_32x32x16_bf16(
                Wf[ctl][ks], Zf[ks], acc[ctl], 0, 0, 0);

    // ---- epilogue: lane l31 owns cols [ch*64, ch*64+64) of its node's row.
    // c = (2*ch+ctl)*32 + 8*g + 4*half + r  for acc[ctl][4*g+r], r = 0..3.
    const int node = nodeBase + l31;
    if (node < nNodes) {
        u16* prow = pq + (size_t)node * 128;
#pragma unroll
        for (int ctl = 0; ctl < 2; ++ctl) {
#pragma unroll
            for (int g = 0; g < 4; ++g) {
                const int c0 = (2 * ch + ctl) * 32 + 8 * g + 4 * half;
                float v0 = acc[ctl][4 * g + 0];
                float v1 = acc[ctl][4 * g + 1];
                float v2 = acc[ctl][4 * g + 2];
                float v3 = acc[ctl][4 * g + 3];
                if (ch == 0) {   // P half gets the bias
                    v0 += b1[c0 + 0]; v1 += b1[c0 + 1];
                    v2 += b1[c0 + 2]; v3 += b1[c0 + 3];
                }
                uint2 st;
                st.x = __builtin_bit_cast(u32, __builtin_amdgcn_cvt_pkrtz(v0, v1));
                st.y = __builtin_bit_cast(u32, __builtin_amdgcn_cvt_pkrtz(v2, v3));
                *(uint2*)(prow + c0) = st;
            }
        }
    }
}

// ---------------------------------------------------------------------------
// Kernel B: edge MLP tail, 8 lanes per edge, packed fp16 math. At the
// fabric roofline: 268 MB (idx 8 + P 128 + Q 128 + out 4) / 6.3 TB/s = 42 us.
//   out[e] = b2 + sum_h W2[h] * relu(P[i][h] + Q[j][h])
// ---------------------------------------------------------------------------
__global__ __launch_bounds__(256) void edge_mlp(
    const int* __restrict__ e0, const int* __restrict__ e1,
    const u16* __restrict__ pq, const float* __restrict__ W2,
    const float* __restrict__ b2, float* __restrict__ out, int E)
{
    const int gid = blockIdx.x * 256 + threadIdx.x;
    const int e   = gid >> 3;
    const int sub = gid & 7;
    if (e >= E) return;

    const int i = e0[e];
    const int j = e1[e];

    const uint4 p = ((const uint4*)(pq + (size_t)i * 128))[sub];
    const uint4 q = ((const uint4*)(pq + (size_t)j * 128 + 64))[sub];

    const float4 wa = ((const float4*)W2)[2 * sub];
    const float4 wb = ((const float4*)W2)[2 * sub + 1];

    const u32 pw[4] = {p.x, p.y, p.z, p.w};
    const u32 qw[4] = {q.x, q.y, q.z, q.w};

    h16x2 w2h[4];
    w2h[0] = (h16x2){(_Float16)wa.x, (_Float16)wa.y};
    w2h[1] = (h16x2){(_Float16)wa.z, (_Float16)wa.w};
    w2h[2] = (h16x2){(_Float16)wb.x, (_Float16)wb.y};
    w2h[3] = (h16x2){(_Float16)wb.z, (_Float16)wb.w};
    const h16x2 hzero = (h16x2){(_Float16)0.0f, (_Float16)0.0f};

    float sum = 0.0f;
#pragma unroll
    for (int c = 0; c < 4; ++c) {
        h16x2 pp = __builtin_bit_cast(h16x2, pw[c]);
        h16x2 qq = __builtin_bit_cast(h16x2, qw[c]);
        h16x2 a  = __builtin_elementwise_max(pp + qq, hzero); // pk_add + pk_max
#if __has_builtin(__builtin_amdgcn_fdot2)
        sum = __builtin_amdgcn_fdot2(a, w2h[c], sum, false);
#else
        sum = fmaf((float)a[0], (float)w2h[c][0],
              fmaf((float)a[1], (float)w2h[c][1], sum));
#endif
    }

    sum += __shfl_xor(sum, 1);
    sum += __shfl_xor(sum, 2);
    sum += __shfl_xor(sum, 4);

    if (sub == 0) out[e] = sum + b2[0];
}

// ---------------------------------------------------------------------------
extern "C" void kernel_launch(void* const* d_in, const int* in_sizes, int n_in,
                              void* d_out, int out_size, void* d_ws, size_t ws_size,
                              hipStream_t stream) {
    const float* z  = (const float*)d_in[0];
    const int*   eg = (const int*)d_in[1];
    const float* W1 = (const float*)d_in[2];
    const float* b1 = (const float*)d_in[3];
    const float* W2 = (const float*)d_in[4];
    const float* b2 = (const float*)d_in[5];
    float* out = (float*)d_out;

    const int nNodes = in_sizes[0] / 64;   // 100000
    const int E      = in_sizes[1] / 2;    // 1000000

    u16* wtab = (u16*)d_ws;                        // 16 KB fragment table
    u16* pq   = (u16*)d_ws + 16384;                // nNodes*128*2 = 25.6 MB

    build_wfrag<<<dim3(32), dim3(256), 0, stream>>>(W1, wtab);

    dim3 gA((nNodes + 127) / 128, 2);      // 4 waves x 32 nodes, col-split x2
    node_mfma<<<gA, dim3(256), 0, stream>>>(z, wtab, b1, pq, nNodes);

    long long tB = (long long)E * 8;       // 8 threads per edge
    dim3 gB((unsigned)((tB + 255) / 256));
    edge_mlp<<<gB, dim3(256), 0, stream>>>(eg, eg + E, pq, W2, b2, out, E);
}